// Round 3
// baseline (1643.325 us; speedup 1.0000x reference)
//
#include <hip/hip_runtime.h>

#define N_USERS 100000
#define N_ITEMS 50000
#define DIM     64
#define N_NODES (N_USERS + N_ITEMS + 1)   /* 150001 */
#define N_EDGES 4800000

static constexpr long long NF = (long long)N_NODES * DIM;   // 9,600,064 floats per tensor

// ------------------- scan geometry -------------------
#define SCAN_T      256
#define SCAN_ITEMS  8
#define SCAN_CHUNK  (SCAN_T * SCAN_ITEMS)                      /* 2048 */
#define SCAN_NBLK   ((N_NODES + SCAN_CHUNK - 1) / SCAN_CHUNK)  /* 74 */

// ------------------- bucket geometry (two-level scatter) -------------------
#define RPB_SHIFT 8
#define RPB       256                                   /* rows per bucket */
#define NBUCKET   ((N_NODES + RPB - 1) / RPB)           /* 586 */
#define BCUR_PAD  16                                    /* 64B stride: one line per cursor */

// ---------------------------------------------------------------------------
// ego = concat(user_emb, item_emb)  (float4-vectorized)
// ---------------------------------------------------------------------------
__global__ void concat_kernel(const float4* __restrict__ user,
                              const float4* __restrict__ item,
                              float4* __restrict__ ego) {
    int i = blockIdx.x * blockDim.x + threadIdx.x;
    const int userF4 = N_USERS * DIM / 4;
    const int totF4  = (int)(NF / 4);
    if (i < userF4)      ego[i] = user[i];
    else if (i < totF4)  ego[i] = item[i - userF4];
}

// ---------------------------------------------------------------------------
// CSR build step 1: histogram of rows
// ---------------------------------------------------------------------------
__global__ void hist_kernel(const int* __restrict__ rows, int* __restrict__ deg) {
    int e = blockIdx.x * blockDim.x + threadIdx.x;
    if (e < N_EDGES) {
        int r = __builtin_nontemporal_load(&rows[e]);
        atomicAdd(&deg[r], 1);
    }
}

// ---------------------------------------------------------------------------
// CSR build step 2a: per-block partial sums of deg
// ---------------------------------------------------------------------------
__global__ void __launch_bounds__(SCAN_T)
scan_a_kernel(const int* __restrict__ deg, int* __restrict__ bsum) {
    __shared__ int lds[SCAN_T];
    int b = blockIdx.x, t = threadIdx.x;
    int base = b * SCAN_CHUNK + t * SCAN_ITEMS;
    int s = 0;
    #pragma unroll
    for (int i = 0; i < SCAN_ITEMS; ++i) {
        int idx = base + i;
        s += (idx < N_NODES) ? deg[idx] : 0;
    }
    lds[t] = s;
    __syncthreads();
    for (int off = SCAN_T / 2; off > 0; off >>= 1) {
        if (t < off) lds[t] += lds[t + off];
        __syncthreads();
    }
    if (t == 0) bsum[b] = lds[0];
}

// ---------------------------------------------------------------------------
// CSR build step 2b: exclusive scan of the 74 block sums
// ---------------------------------------------------------------------------
__global__ void __launch_bounds__(128)
scan_b_kernel(const int* __restrict__ bsum, int* __restrict__ boff) {
    __shared__ int lds[128];
    int t = threadIdx.x;
    lds[t] = (t < SCAN_NBLK) ? bsum[t] : 0;
    __syncthreads();
    for (int off = 1; off < 128; off <<= 1) {
        int x = lds[t];
        int y = (t >= off) ? lds[t - off] : 0;
        __syncthreads();
        lds[t] = x + y;
        __syncthreads();
    }
    if (t < SCAN_NBLK) boff[t] = (t == 0) ? 0 : lds[t - 1];
}

// ---------------------------------------------------------------------------
// CSR build step 2c: row_ptr + cursor + per-bucket base cursors
// ---------------------------------------------------------------------------
__global__ void __launch_bounds__(SCAN_T)
scan_c_kernel(const int* __restrict__ deg, const int* __restrict__ boff,
              int* __restrict__ row_ptr, int* __restrict__ cursor,
              int* __restrict__ bcur) {
    __shared__ int lds[SCAN_T];
    int b = blockIdx.x, t = threadIdx.x;
    int base = b * SCAN_CHUNK + t * SCAN_ITEMS;
    int v[SCAN_ITEMS];
    int s = 0;
    #pragma unroll
    for (int i = 0; i < SCAN_ITEMS; ++i) {
        int idx = base + i;
        int d = (idx < N_NODES) ? deg[idx] : 0;
        v[i] = s;
        s += d;
    }
    lds[t] = s;
    __syncthreads();
    for (int off = 1; off < SCAN_T; off <<= 1) {
        int x = lds[t];
        int y = (t >= off) ? lds[t - off] : 0;
        __syncthreads();
        lds[t] = x + y;
        __syncthreads();
    }
    int toff = ((t == 0) ? 0 : lds[t - 1]) + boff[b];
    #pragma unroll
    for (int i = 0; i < SCAN_ITEMS; ++i) {
        int idx = base + i;
        if (idx < N_NODES) {
            int val = v[i] + toff;
            row_ptr[idx] = val;
            cursor[idx]  = val;
            if ((idx & (RPB - 1)) == 0) bcur[(idx >> RPB_SHIFT) * BCUR_PAD] = val;
        }
    }
    if (b == 0 && t == 0) row_ptr[N_NODES] = N_EDGES;
}

// ---------------------------------------------------------------------------
// Scatter pass 1: bin edges into 586 row-range buckets at CSR base offsets.
// Packed tmp edge: x = (row_local<<18)|col, y = val bits.
// 586 sequential write heads -> lines fill before eviction.
// ---------------------------------------------------------------------------
__global__ void bin_kernel(const int* __restrict__ rows,
                           const int* __restrict__ cols,
                           const float* __restrict__ vals,
                           int* __restrict__ bcur,
                           uint2* __restrict__ tmp) {
    int e = blockIdx.x * blockDim.x + threadIdx.x;
    if (e < N_EDGES) {
        int   r = __builtin_nontemporal_load(&rows[e]);
        int   c = __builtin_nontemporal_load(&cols[e]);
        float v = __builtin_nontemporal_load(&vals[e]);
        int   b = r >> RPB_SHIFT;
        int   p = atomicAdd(&bcur[b * BCUR_PAD], 1);
        tmp[p] = make_uint2(((unsigned)(r & (RPB - 1)) << 18) | (unsigned)c,
                            __float_as_uint(v));
    }
}

// ---------------------------------------------------------------------------
// Scatter pass 2: one block per bucket; permute within an L2-resident ~65KB
// range into exact CSR order.
// ---------------------------------------------------------------------------
__global__ void __launch_bounds__(256)
scatter2_kernel(const int* __restrict__ row_ptr,
                const uint2* __restrict__ tmp,
                int* __restrict__ cursor,
                uint2* __restrict__ edges) {
    int b      = blockIdx.x;
    int lo_row = b << RPB_SHIFT;
    int hi_row = min(lo_row + RPB, N_NODES);
    int base   = row_ptr[lo_row];
    int cnt    = row_ptr[hi_row] - base;
    for (int i = threadIdx.x; i < cnt; i += 256) {
        unsigned long long w =
            __builtin_nontemporal_load((const unsigned long long*)(tmp + base + i));
        unsigned x = (unsigned)w;
        int r = lo_row + (int)(x >> 18);
        int p = atomicAdd(&cursor[r], 1);
        edges[p] = make_uint2(x & 0x3FFFFu, (unsigned)(w >> 32));
    }
}

// ---------------------------------------------------------------------------
// CSR SpMM: one wave per row; lane d owns dim d. 8-deep unrolled gathers,
// nontemporal edge loads (don't evict the h-table from L2).
// ---------------------------------------------------------------------------
__global__ void __launch_bounds__(256)
spmm_csr_kernel(const int* __restrict__ row_ptr,
                const uint2* __restrict__ edges,
                const float* __restrict__ hin,
                float* __restrict__ hout) {
    int wave = (blockIdx.x * blockDim.x + threadIdx.x) >> 6;
    int lane = threadIdx.x & 63;
    if (wave >= N_NODES) return;
    int start = row_ptr[wave];
    int end   = row_ptr[wave + 1];
    float a[8] = {0.f, 0.f, 0.f, 0.f, 0.f, 0.f, 0.f, 0.f};
    int e = start;
    for (; e + 8 <= end; e += 8) {
        #pragma unroll
        for (int k = 0; k < 8; ++k) {
            unsigned long long w =
                __builtin_nontemporal_load((const unsigned long long*)(edges + e + k));
            a[k] += __uint_as_float((unsigned)(w >> 32)) *
                    hin[(int)((unsigned)w) * DIM + lane];
        }
    }
    for (; e < end; ++e) {
        unsigned long long w =
            __builtin_nontemporal_load((const unsigned long long*)(edges + e));
        a[0] += __uint_as_float((unsigned)(w >> 32)) *
                hin[(int)((unsigned)w) * DIM + lane];
    }
    hout[wave * DIM + lane] = ((a[0] + a[1]) + (a[2] + a[3])) +
                              ((a[4] + a[5]) + (a[6] + a[7]));
}

// ---------------------------------------------------------------------------
// CSR SpMM (last layer) fused with h_sum = ego + h1 + h2 + h3
// ---------------------------------------------------------------------------
__global__ void __launch_bounds__(256)
spmm_csr_fused_kernel(const int* __restrict__ row_ptr,
                      const uint2* __restrict__ edges,
                      const float* __restrict__ h2,
                      const float* __restrict__ ego,
                      const float* __restrict__ h1,
                      float* __restrict__ h3,
                      float* __restrict__ hsum) {
    int wave = (blockIdx.x * blockDim.x + threadIdx.x) >> 6;
    int lane = threadIdx.x & 63;
    if (wave >= N_NODES) return;
    int start = row_ptr[wave];
    int end   = row_ptr[wave + 1];
    float a[8] = {0.f, 0.f, 0.f, 0.f, 0.f, 0.f, 0.f, 0.f};
    int e = start;
    for (; e + 8 <= end; e += 8) {
        #pragma unroll
        for (int k = 0; k < 8; ++k) {
            unsigned long long w =
                __builtin_nontemporal_load((const unsigned long long*)(edges + e + k));
            a[k] += __uint_as_float((unsigned)(w >> 32)) *
                    h2[(int)((unsigned)w) * DIM + lane];
        }
    }
    for (; e < end; ++e) {
        unsigned long long w =
            __builtin_nontemporal_load((const unsigned long long*)(edges + e));
        a[0] += __uint_as_float((unsigned)(w >> 32)) *
                h2[(int)((unsigned)w) * DIM + lane];
    }
    float acc = ((a[0] + a[1]) + (a[2] + a[3])) + ((a[4] + a[5]) + (a[6] + a[7]));
    int o = wave * DIM + lane;
    float ve = __builtin_nontemporal_load(&ego[o]);
    float v1 = __builtin_nontemporal_load(&h1[o]);
    h3[o]   = acc;
    hsum[o] = ve + v1 + h2[o] + acc;
}

// ---------------------------------------------------------------------------
// Fallback SpMM via fp32 atomics (used only if ws_size too small for CSR)
// ---------------------------------------------------------------------------
__global__ void spmm_atomic_kernel(const int* __restrict__ rows,
                                   const int* __restrict__ cols,
                                   const float* __restrict__ vals,
                                   const float* __restrict__ hin,
                                   float* __restrict__ hout) {
    int e = blockIdx.x * 4 + (threadIdx.x >> 6);
    int d = threadIdx.x & 63;
    if (e < N_EDGES) {
        atomicAdd(&hout[rows[e] * DIM + d], vals[e] * hin[cols[e] * DIM + d]);
    }
}

__global__ void sum_kernel(const float4* __restrict__ a,
                           const float4* __restrict__ b,
                           const float4* __restrict__ c,
                           const float4* __restrict__ d,
                           float4* __restrict__ out) {
    int i = blockIdx.x * blockDim.x + threadIdx.x;
    if (i < (int)(NF / 4)) {
        float4 x = a[i], y = b[i], z = c[i], w = d[i];
        out[i] = make_float4(x.x + y.x + z.x + w.x,
                             x.y + y.y + z.y + w.y,
                             x.z + y.z + z.z + w.z,
                             x.w + y.w + z.w + w.w);
    }
}

extern "C" void kernel_launch(void* const* d_in, const int* in_sizes, int n_in,
                              void* d_out, int out_size, void* d_ws, size_t ws_size,
                              hipStream_t stream) {
    const float* user = (const float*)d_in[0];
    const float* item = (const float*)d_in[1];
    const float* vals = (const float*)d_in[2];
    const int*   rows = (const int*)d_in[3];
    const int*   cols = (const int*)d_in[4];

    float* out  = (float*)d_out;
    float* hsum = out;
    float* ego  = out + NF;
    float* h1   = out + 2 * NF;
    float* h2   = out + 3 * NF;
    float* h3   = out + 4 * NF;

    const int totF4 = (int)(NF / 4);

    // workspace layout: final edges first (8B aligned), then int arrays
    const size_t nInt = (size_t)(N_NODES + 2);
    size_t need = (size_t)N_EDGES * 8 +
                  (3 * nInt + 2 * 128 + (size_t)NBUCKET * BCUR_PAD) * 4;  // ~40.3 MB

    if (ws_size >= need) {
        uint2* edges   = (uint2*)d_ws;
        int*   deg     = (int*)(edges + N_EDGES);
        int*   row_ptr = deg + nInt;
        int*   cursor  = row_ptr + nInt;
        int*   bsum    = cursor + nInt;
        int*   boff    = bsum + 128;
        int*   bcur    = boff + 128;
        // temp binned edges live in the not-yet-written h3 output slice
        uint2* tmp     = (uint2*)h3;

        hipMemsetAsync(deg, 0, (size_t)N_NODES * sizeof(int), stream);
        hist_kernel<<<(N_EDGES + 255) / 256, 256, 0, stream>>>(rows, deg);
        scan_a_kernel<<<SCAN_NBLK, SCAN_T, 0, stream>>>(deg, bsum);
        scan_b_kernel<<<1, 128, 0, stream>>>(bsum, boff);
        scan_c_kernel<<<SCAN_NBLK, SCAN_T, 0, stream>>>(deg, boff, row_ptr, cursor, bcur);
        bin_kernel<<<(N_EDGES + 255) / 256, 256, 0, stream>>>(rows, cols, vals, bcur, tmp);
        scatter2_kernel<<<NBUCKET, 256, 0, stream>>>(row_ptr, tmp, cursor, edges);

        // concat right before spmm1 so ego is warm in cache
        concat_kernel<<<(totF4 + 255) / 256, 256, 0, stream>>>(
            (const float4*)user, (const float4*)item, (float4*)ego);

        const int spmmBlocks = (N_NODES * 64 + 255) / 256;  // 1 wave per row
        spmm_csr_kernel<<<spmmBlocks, 256, 0, stream>>>(row_ptr, edges, ego, h1);
        spmm_csr_kernel<<<spmmBlocks, 256, 0, stream>>>(row_ptr, edges, h1,  h2);
        spmm_csr_fused_kernel<<<spmmBlocks, 256, 0, stream>>>(
            row_ptr, edges, h2, ego, h1, h3, hsum);
    } else {
        concat_kernel<<<(totF4 + 255) / 256, 256, 0, stream>>>(
            (const float4*)user, (const float4*)item, (float4*)ego);
        hipMemsetAsync(h1, 0, (size_t)(3 * NF) * sizeof(float), stream);
        const int ablocks = (N_EDGES + 3) / 4;
        spmm_atomic_kernel<<<ablocks, 256, 0, stream>>>(rows, cols, vals, ego, h1);
        spmm_atomic_kernel<<<ablocks, 256, 0, stream>>>(rows, cols, vals, h1,  h2);
        spmm_atomic_kernel<<<ablocks, 256, 0, stream>>>(rows, cols, vals, h2,  h3);
        sum_kernel<<<(totF4 + 255) / 256, 256, 0, stream>>>(
            (const float4*)ego, (const float4*)h1, (const float4*)h2, (const float4*)h3,
            (float4*)hsum);
    }
}